// Round 1
// baseline (446.694 us; speedup 1.0000x reference)
//
#include <hip/hip_runtime.h>

#define KDIM 1024
#define NOUT 15
#define NEXP 10
#define BM   64
#define NKS  32            // KDIM / 32
#define QPT  20            // 16B fragment groups per k-slab: (n-tile 0..9) x (kt 0..1)
#define SCOL 305           // epilogue scratch stride (fp32)

typedef short bf16x8 __attribute__((ext_vector_type(8)));
typedef float f32x16 __attribute__((ext_vector_type(16)));

// round-to-nearest-even fp32 -> bf16 pair packed into one dword
__device__ __forceinline__ unsigned f2bf2(float a, float b) {
    unsigned ua = __float_as_uint(a);
    unsigned ub = __float_as_uint(b);
    ua = (ua + 0x7FFFu + ((ua >> 16) & 1u)) >> 16;
    ub = (ub + 0x7FFFu + ((ub >> 16) & 1u)) & 0xFFFF0000u;
    return ua | ub;
}

// ---- pre-pass: W (expert+gate) fp32 -> bf16 workspace in exact B-fragment order ----
// unit U (16B, 8 bf16): L = U&63, q = (U>>6)%QPT, ks = U/(QPT*64)
//   nt = q>>1 (global n-tile), kt = q&1
//   B-frag lane L holds W[row = nt*32 + (L&31)][k = ks*32 + kt*16 + (L>>5)*8 + 0..7]
__global__ void wconv_kernel(const float* __restrict__ ew,
                             const float* __restrict__ gw,
                             unsigned short* __restrict__ ws)
{
    int U  = blockIdx.x * 256 + threadIdx.x;    // 0 .. 40959
    int L  = U & 63;
    int q  = (U >> 6) % QPT;
    int ks = U / (QPT * 64);
    int nt = q >> 1, kt = q & 1;
    int wrow = nt * 32 + (L & 31);
    int wcol = ks * 32 + kt * 16 + (L >> 5) * 8;
    float4 a = {0.f,0.f,0.f,0.f}, b = {0.f,0.f,0.f,0.f};
    if (wrow < 150) {
        a = *(const float4*)(ew + wrow * KDIM + wcol);
        b = *(const float4*)(ew + wrow * KDIM + wcol + 4);
    } else if (wrow < 300) {
        a = *(const float4*)(gw + (wrow - 150) * KDIM + wcol);
        b = *(const float4*)(gw + (wrow - 150) * KDIM + wcol + 4);
    }
    uint4 o;
    o.x = f2bf2(a.x, a.y); o.y = f2bf2(a.z, a.w);
    o.z = f2bf2(b.x, b.y); o.w = f2bf2(b.z, b.w);
    *(uint4*)(ws + (size_t)U * 8) = o;
}

__global__ void __launch_bounds__(256, 3)
moe_kernel(const float* __restrict__ x,
           const unsigned short* __restrict__ wsrc,
           const float* __restrict__ eb,
           const float* __restrict__ gb,
           float* __restrict__ out)
{
    // epilogue scratch only -- K loop uses NO LDS and NO barriers
    __shared__ float ep[32][SCOL];             // 39040 B

    const int tid = threadIdx.x;
    const int wv  = tid >> 6;
    const int L   = tid & 63;
    const int mw  = wv >> 1;      // 0..1 : which 32-row half
    const int nw  = wv & 1;       // 0..1 : n-tiles nw*5 .. nw*5+4 (160 cols)
    const int ln  = L & 31;       // MFMA row (A) / col (B, C/D)
    const int lh  = L >> 5;       // k-half selector within fragment

    // this lane's X row pointer (frag k-offset baked in)
    const float* xrow = x + ((size_t)blockIdx.x * BM + mw * 32 + ln) * KDIM + lh * 8;
    // this lane's B-fragment base: workspace is laid out as [ks][q][L] 16B units
    const bf16x8* wf = (const bf16x8*)wsrc + L;

    f32x16 acc[5];
    #pragma unroll
    for (int nt = 0; nt < 5; ++nt)
        #pragma unroll
        for (int r = 0; r < 16; ++r)
            acc[nt][r] = 0.f;

    // ---- prologue: load A slab 0 ----
    float4 xa[2][2];
    #pragma unroll
    for (int kt = 0; kt < 2; ++kt) {
        xa[kt][0] = *(const float4*)(xrow + kt * 16);
        xa[kt][1] = *(const float4*)(xrow + kt * 16 + 4);
    }

    // ---- K loop: 32 slabs, barrier-free; W fragments read straight from L2 ----
    #pragma unroll 2
    for (int ks = 0; ks < NKS; ++ks) {
        float4 xn[2][2];
        if (ks + 1 < NKS) {
            #pragma unroll
            for (int kt = 0; kt < 2; ++kt) {
                xn[kt][0] = *(const float4*)(xrow + (ks + 1) * 32 + kt * 16);
                xn[kt][1] = *(const float4*)(xrow + (ks + 1) * 32 + kt * 16 + 4);
            }
        }

        bf16x8 af[2];
        #pragma unroll
        for (int kt = 0; kt < 2; ++kt) {
            union { unsigned u[4]; bf16x8 v; } pk;
            pk.u[0] = f2bf2(xa[kt][0].x, xa[kt][0].y);
            pk.u[1] = f2bf2(xa[kt][0].z, xa[kt][0].w);
            pk.u[2] = f2bf2(xa[kt][1].x, xa[kt][1].y);
            pk.u[3] = f2bf2(xa[kt][1].z, xa[kt][1].w);
            af[kt] = pk.v;
        }

        #pragma unroll
        for (int nt = 0; nt < 5; ++nt) {
            #pragma unroll
            for (int kt = 0; kt < 2; ++kt) {
                int q = (nw * 5 + nt) * 2 + kt;
                bf16x8 bf = wf[((size_t)ks * QPT + q) * 64];
                acc[nt] = __builtin_amdgcn_mfma_f32_32x32x16_bf16(af[kt], bf, acc[nt], 0, 0, 0);
            }
        }

        #pragma unroll
        for (int kt = 0; kt < 2; ++kt) {
            xa[kt][0] = xn[kt][0];
            xa[kt][1] = xn[kt][1];
        }
    }

    // ---- epilogue: two 32-row phases through LDS scratch ----
    #pragma unroll 1
    for (int g = 0; g < 2; ++g) {
        if (mw == g) {
            // 32x32 C/D layout: col = lane&31, row = (reg&3) + 8*(reg>>2) + 4*(lane>>5)
            #pragma unroll
            for (int nt = 0; nt < 5; ++nt) {
                int col = nw * 160 + nt * 32 + ln;
                if (col < 300) {
                    #pragma unroll
                    for (int r = 0; r < 16; ++r)
                        ep[(r & 3) + 8 * (r >> 2) + 4 * lh][col] = acc[nt][r];
                }
            }
        }
        __syncthreads();

        #pragma unroll 1
        for (int t = tid; t < 32 * NOUT; t += 256) {
            int row = t / NOUT, o = t % NOUT;
            float xi[NEXP], miu_v[NEXP];
            float mx = -1e30f;
            #pragma unroll
            for (int e = 0; e < NEXP; ++e) {
                miu_v[e] = ep[row][e * NOUT + o]       + eb[e * NOUT + o];
                xi[e]    = ep[row][150 + e * NOUT + o] + gb[e * NOUT + o];
                mx = fmaxf(mx, xi[e]);
            }
            float s = 0.f, v = 0.f;
            #pragma unroll
            for (int e = 0; e < NEXP; ++e) {
                float g2 = __expf(xi[e] - mx);
                s += g2;
                v += g2 * miu_v[e];
            }
            out[((size_t)blockIdx.x * BM + g * 32 + row) * NOUT + o] = v / s;
        }
        __syncthreads();
    }
}

extern "C" void kernel_launch(void* const* d_in, const int* in_sizes, int n_in,
                              void* d_out, int out_size, void* d_ws, size_t ws_size,
                              hipStream_t stream) {
    const float* x  = (const float*)d_in[0];
    const float* ew = (const float*)d_in[1];
    const float* eb = (const float*)d_in[2];
    const float* gw = (const float*)d_in[3];
    const float* gb = (const float*)d_in[4];
    float* out = (float*)d_out;
    unsigned short* ws = (unsigned short*)d_ws;   // NKS*QPT*64*16B = 640 KB

    wconv_kernel<<<160, 256, 0, stream>>>(ew, gw, ws);
    moe_kernel<<<65536 / BM, 256, 0, stream>>>(x, ws, eb, gb, out);
}